// Round 3
// baseline (1448.515 us; speedup 1.0000x reference)
//
#include <hip/hip_runtime.h>

// RNN scan: h <- tanh(x_t @ W_ih^T + h @ W_hh^T + b), 2048 steps, 1 block/batch,
// 256 threads = 16 rowgroups (8 rows) x 16 colgroups (8 cols). Thread (g,c) owns
// an 8x8 tile of both W matrices in ARCH VGPRs (pinned via empty asm each step).
// Per step: 4 ds_read_b128 + 128 v_fmac + cndmask-free DPP butterfly reduction
// (W rows loaded pre-permuted by r^p) + predicated ds_write_b64 + 1 barrier.
// x and h LDS rows padded p(col)=col+4*(col>>3) (stride 192) -> 2-way aliasing only.

#define BATCH 256
#define SEQ   2048
#define HID   128
#define CH    16
#define NCHUNK (SEQ / CH)
#define XPAD  192

// quad_perm[1,0,3,2]=0xB1 (xor1), quad_perm[2,3,0,1]=0x4E (xor2),
// row_ror:4=0x124, row_ror:8=0x128
template <int CTRL>
__device__ __forceinline__ float dpp_movf(float x) {
    return __int_as_float(__builtin_amdgcn_mov_dpp(__float_as_int(x), CTRL, 0xF, 0xF, true));
}

__device__ __forceinline__ float tanh_fast(float x) {
    x = fminf(fmaxf(x, -12.0f), 12.0f);
    float e = __expf(2.0f * x);
    return 1.0f - __fdividef(2.0f, e + 1.0f);
}

#define PIN4(v) asm volatile("" : "+v"(v.x), "+v"(v.y), "+v"(v.z), "+v"(v.w))

__global__ __launch_bounds__(256)
__attribute__((amdgpu_waves_per_eu(1)))
void rnn_scan_kernel(
    const float* __restrict__ x,    // [B, S, 128]
    const float* __restrict__ Wih,  // [128, 128]
    const float* __restrict__ bih,  // [128]
    const float* __restrict__ Whh,  // [128, 128]
    const float* __restrict__ bhh,  // [128]
    float* __restrict__ out)        // [B, 128]
{
    const int b = blockIdx.x;
    const int t = threadIdx.x;
    const int g = t >> 4;          // rowgroup: rows 8g..8g+7
    const int c = t & 15;          // colgroup: cols 8c..8c+7
    const int colbase = c << 3;
    const int xoff = 12 * c;       // padded word of col 8c

    __shared__ __align__(16) float xbuf[2][CH * XPAD]; // 24 KB
    __shared__ __align__(16) float hbuf[2][XPAD];      // 1.5 KB

    // Butterfly-permuted W rows: slot r holds row 8g + (r ^ p).
    const int p = ((c & 1) << 2) | (c & 2);   // 0,4,2,6 for c&3 = 0..3
    float4 wi[8][2], wh[8][2];
#pragma unroll
    for (int r = 0; r < 8; ++r) {
        const int row = (g << 3) + (r ^ p);
        const float* pi = Wih + row * HID + colbase;
        const float* ph = Whh + row * HID + colbase;
        wi[r][0] = *(const float4*)(pi);
        wi[r][1] = *(const float4*)(pi + 4);
        wh[r][0] = *(const float4*)(ph);
        wh[r][1] = *(const float4*)(ph + 4);
    }

    const int row0 = (g << 3) + p;            // lane ends with rows row0, row0+1
    const float bias0 = bih[row0] + bhh[row0];
    const float bias1 = bih[row0 + 1] + bhh[row0 + 1];
    const int hw = 12 * g + p;                // padded word of row0 (even)

    // padded staging dests (fixed per thread): float4 q -> step q>>5, m=q&31,
    // word = 192*(q>>5) + 12*(m>>1) + 4*(m&1)
    const int m0 = t & 31;
    const int dst0 = XPAD * (t >> 5) + 12 * (m0 >> 1) + ((m0 & 1) << 2);
    const int dst1 = dst0 + XPAD * 8;         // q = t + 256

    const float* xsrc = x + (size_t)b * (SEQ * HID);

    {   // prologue: stage chunk 0
        const float4* gp = (const float4*)xsrc;
        float4 p0 = gp[t], p1 = gp[256 + t];
        *(float4*)&xbuf[0][dst0] = p0;
        *(float4*)&xbuf[0][dst1] = p1;
    }
    if (t < XPAD) hbuf[0][t] = 0.0f;
    __syncthreads();

    int cur = 0;
    for (int chn = 0; chn < NCHUNK; ++chn) {
        float4 q0, q1;
        const bool pf = (chn + 1 < NCHUNK);
        if (pf) {
            const float4* gp = (const float4*)(xsrc + (size_t)(chn + 1) * (CH * HID));
            q0 = gp[t];
            q1 = gp[256 + t];
        }
        const float* xb = &xbuf[chn & 1][0];
#pragma unroll 1
        for (int s = 0; s < CH; ++s) {
            // pin W tiles in arch VGPRs (empty asm: zero instructions if honored)
#pragma unroll
            for (int r = 0; r < 8; ++r) {
                PIN4(wi[r][0]); PIN4(wi[r][1]);
                PIN4(wh[r][0]); PIN4(wh[r][1]);
            }
            const float* hr = &hbuf[cur][xoff];
            float4 hv0 = *(const float4*)(hr);
            float4 hv1 = *(const float4*)(hr + 4);
            const float* xr = xb + s * XPAD + xoff;
            float4 xv0 = *(const float4*)(xr);
            float4 xv1 = *(const float4*)(xr + 4);

            float a[8];
            // x-part first: independent of h -> hides post-barrier h-read latency
#pragma unroll
            for (int r = 0; r < 8; ++r) {
                float acc;
                acc = wi[r][0].x * xv0.x;
                acc = fmaf(wi[r][0].y, xv0.y, acc);
                acc = fmaf(wi[r][0].z, xv0.z, acc);
                acc = fmaf(wi[r][0].w, xv0.w, acc);
                acc = fmaf(wi[r][1].x, xv1.x, acc);
                acc = fmaf(wi[r][1].y, xv1.y, acc);
                acc = fmaf(wi[r][1].z, xv1.z, acc);
                acc = fmaf(wi[r][1].w, xv1.w, acc);
                a[r] = acc;
            }
#pragma unroll
            for (int r = 0; r < 8; ++r) {
                float acc = a[r];
                acc = fmaf(wh[r][0].x, hv0.x, acc);
                acc = fmaf(wh[r][0].y, hv0.y, acc);
                acc = fmaf(wh[r][0].z, hv0.z, acc);
                acc = fmaf(wh[r][0].w, hv0.w, acc);
                acc = fmaf(wh[r][1].x, hv1.x, acc);
                acc = fmaf(wh[r][1].y, hv1.y, acc);
                acc = fmaf(wh[r][1].z, hv1.z, acc);
                acc = fmaf(wh[r][1].w, hv1.w, acc);
                a[r] = acc;
            }

            // cndmask-free butterfly reduce-scatter over the 16 col-lanes
            float t0 = a[0] + dpp_movf<0xB1>(a[4]);
            float t1 = a[1] + dpp_movf<0xB1>(a[5]);
            float t2 = a[2] + dpp_movf<0xB1>(a[6]);
            float t3 = a[3] + dpp_movf<0xB1>(a[7]);
            float u0 = t0 + dpp_movf<0x4E>(t2);
            float u1 = t1 + dpp_movf<0x4E>(t3);
            u0 += dpp_movf<0x124>(u0);
            u1 += dpp_movf<0x124>(u1);
            u0 += dpp_movf<0x128>(u0);
            u1 += dpp_movf<0x128>(u1);

            if (c < 4) {   // lanes c>=4 hold duplicates
                float h0 = tanh_fast(u0 + bias0);
                float h1 = tanh_fast(u1 + bias1);
                *(float2*)&hbuf[cur ^ 1][hw] = make_float2(h0, h1);
            }

            if (s == CH - 1 && pf) {
                float* nb = &xbuf[(chn + 1) & 1][0];
                *(float4*)&nb[dst0] = q0;
                *(float4*)&nb[dst1] = q1;
            }
            __syncthreads();
            cur ^= 1;
        }
    }
    // cur == 0; hbuf[0] holds h_final in padded layout
    if (t < HID) out[(size_t)b * HID + t] = hbuf[cur][t + ((t >> 3) << 2)];
}

extern "C" void kernel_launch(void* const* d_in, const int* in_sizes, int n_in,
                              void* d_out, int out_size, void* d_ws, size_t ws_size,
                              hipStream_t stream) {
    const float* x   = (const float*)d_in[0];
    const float* Wih = (const float*)d_in[1];
    const float* bih = (const float*)d_in[2];
    const float* Whh = (const float*)d_in[3];
    const float* bhh = (const float*)d_in[4];
    float* out = (float*)d_out;

    rnn_scan_kernel<<<BATCH, 256, 0, stream>>>(x, Wih, bih, Whh, bhh, out);
}